// Round 4
// baseline (247.559 us; speedup 1.0000x reference)
//
#include <hip/hip_runtime.h>

// LSTM B=8192, T=168, P=16, H=24, gates [i,f,g,o].
// Round-13: BARRIER-FREE — one wave owns 16 batches end-to-end.
//  - r12 post-mortem: step pinned ~1400 cyc regardless of waves/SIMD (r10
//    2/SIMD=1436, r12 4/SIMD=1405). Busy cyc == issue estimate; the ~720
//    residual is the per-step __syncthreads convoy + LDS h-exchange chain,
//    which extra waves cannot hide (all waves lockstep on one recurrence).
//  - Fix: self-contained MFMA dataflow. Row perm: row rho of tile tau =
//    gate (rho&3) of unit 6*(rho>>2)+tau  ->  lane (q,n) gets C rows
//    4q..4q+3 of all 6 tiles = gates of units 6q..6q+5 (6 cells/lane,
//    96 rows exact). K-map: B1 slot 8q+j = h-unit 6q+j (j<6; j=6,7 pad)
//    ->  lane supplies exactly the 6 h it computed. h never leaves the
//    lane: B1 = 6 f16 casts. NO LDS / shuffles / barriers in the T-loop.
//  - x read straight from global (q<2 lanes: 32B each, 64B/batch-row
//    coalesced), software-pipelined 3 steps (~2000 cyc) ahead.
//  - 512 waves (8192/16) = 256 blocks x 128 thr = 1 block/CU, 2 waves on
//    2 SIMDs. New wall: trans issue 42*16=672 cyc/step.
//  - Cell math identical to r10/r12 (fused-denominator, 7 trans/cell).

#define T_STEPS 168
#define P_FEAT  16

typedef _Float16 half8 __attribute__((ext_vector_type(8)));
typedef float    f32x4 __attribute__((ext_vector_type(4)));

__device__ __forceinline__ float rcp_fast(float x) {
#if __has_builtin(__builtin_amdgcn_rcpf)
    return __builtin_amdgcn_rcpf(x);
#else
    return 1.0f / x;
#endif
}
__device__ __forceinline__ float exp2_fast(float x) {
#if __has_builtin(__builtin_amdgcn_exp2f)
    return __builtin_amdgcn_exp2f(x);
#else
    return exp2f(x);
#endif
}
__device__ __forceinline__ float tanh_f(float x) {
    return 1.0f - 2.0f * rcp_fast(1.0f + exp2_fast(x * 2.88539008f));
}

__global__ __launch_bounds__(128, 1) void lstm_bf(
    const float* __restrict__ x,
    const float* __restrict__ W_ih,
    const float* __restrict__ W_hh,
    const float* __restrict__ b_ih,
    const float* __restrict__ b_hh,
    const float* __restrict__ W_lin,
    const float* __restrict__ b_lin,
    float* __restrict__ out)
{
    __shared__ float thbuf[2][16][25];   // epilogue only (pad 25: stride coprime 32)

    const int tid  = threadIdx.x;
    const int wv   = tid >> 6;           // wave 0..1
    const int lane = tid & 63;
    const int n    = lane & 15;          // batch col (B/C) == A row supplied
    const int q    = lane >> 4;          // k-chunk == C row-quad
    const int batch = blockIdx.x * 32 + wv * 16 + n;

    // ---- A-fragments (per-lane, direct from global; one-time) ----
    // A row m=n of tile tau: W row grow = gate (n&3) of unit 6*(n>>2)+tau.
    // A1 col j (k=8q+j): W_hh[grow][6q+j] for j<6, pad j=6,7.
    // A2 col j: W_ih[grow][8q+j] for 8q+j<16 (q<2), else 0.
    half8 A1[6], A2[6];
    f32x4 biasf[6];
    #pragma unroll
    for (int tau = 0; tau < 6; tau++) {
        const int grow = (n & 3) * 24 + 6 * (n >> 2) + tau;
        #pragma unroll
        for (int j = 0; j < 8; j++) {
            A1[tau][j] = (j < 6) ? (_Float16)W_hh[grow * 24 + 6 * q + j] : (_Float16)0.0f;
            const int k = 8 * q + j;
            A2[tau][j] = (k < 16) ? (_Float16)W_ih[grow * 16 + k] : (_Float16)0.0f;
        }
        const int u = 6 * q + tau;       // this lane's unit for tile tau
        #pragma unroll
        for (int r = 0; r < 4; r++)
            biasf[tau][r] = b_ih[r * 24 + u] + b_hh[r * 24 + u];
    }

    float c[6]  = {0.0f, 0.0f, 0.0f, 0.0f, 0.0f, 0.0f};
    float hv[6] = {0.0f, 0.0f, 0.0f, 0.0f, 0.0f, 0.0f};
    half8 B1 = {};                        // h_{-1}=0; slots 6,7 stay 0 forever

    const float* xrow = x + (size_t)batch * (T_STEPS * P_FEAT) + 8 * q;

    float4 xa0 = {0,0,0,0}, xa1 = {0,0,0,0};
    float4 xb0 = {0,0,0,0}, xb1 = {0,0,0,0};
    float4 xc0 = {0,0,0,0}, xc1 = {0,0,0,0};

    auto xload = [&](int t, float4& r0, float4& r1) {
        if (q < 2) {
            const float4* p = reinterpret_cast<const float4*>(xrow + (size_t)t * P_FEAT);
            r0 = p[0];
            r1 = p[1];
        }
    };
    auto mkB2 = [&](const float4& r0, const float4& r1) -> half8 {
        half8 b = {};
        if (q < 2) {
            b[0] = (_Float16)r0.x; b[1] = (_Float16)r0.y;
            b[2] = (_Float16)r0.z; b[3] = (_Float16)r0.w;
            b[4] = (_Float16)r1.x; b[5] = (_Float16)r1.y;
            b[6] = (_Float16)r1.z; b[7] = (_Float16)r1.w;
        }
        return b;
    };

    f32x4 gx[6];

    auto do_step = [&](const half8 B2n) {
        f32x4 g[6];
        #pragma unroll
        for (int s = 0; s < 6; s++)
            g[s] = __builtin_amdgcn_mfma_f32_16x16x32_f16(A1[s], B1, gx[s], 0, 0, 0);
        #pragma unroll
        for (int s = 0; s < 6; s++)
            gx[s] = __builtin_amdgcn_mfma_f32_16x16x32_f16(A2[s], B2n, biasf[s], 0, 0, 0);
        // fused-denominator activations: 7 trans per cell
        //   c' = [c(1+Y)(1+Z) + (1+X)(Z-1)] * rcp((1+X)(1+Y)(1+Z))
        //   h  = (W-1) * rcp((1+V)(1+W)),  W = e^{2*min(c',18)}
        #pragma unroll
        for (int s = 0; s < 6; s++) {
            const float Y  = exp2_fast(g[s][0] * -1.44269504f);  // i
            const float X  = exp2_fast(g[s][1] * -1.44269504f);  // f
            const float Z  = exp2_fast(g[s][2] *  2.88539008f);  // g
            const float V  = exp2_fast(g[s][3] * -1.44269504f);  // o
            const float ax = 1.0f + X;
            const float ay = 1.0f + Y;
            const float az = 1.0f + Z;
            const float num = c[s] * ay * az + ax * (Z - 1.0f);
            const float cn  = num * rcp_fast(ax * ay * az);
            c[s] = cn;
            const float W  = exp2_fast(fminf(cn, 18.0f) * 2.88539008f);
            hv[s] = (W - 1.0f) * rcp_fast((1.0f + V) * (1.0f + W));
        }
        // repack own h -> B1 for next step (in-register, no exchange)
        B1[0] = (_Float16)hv[0]; B1[1] = (_Float16)hv[1];
        B1[2] = (_Float16)hv[2]; B1[3] = (_Float16)hv[3];
        B1[4] = (_Float16)hv[4]; B1[5] = (_Float16)hv[5];
    };

    // ---- prologue: 3-deep x pipeline + gx(t=0) ----
    xload(0, xa0, xa1);
    xload(1, xb0, xb1);
    xload(2, xc0, xc1);
    {
        const half8 B20 = mkB2(xa0, xa1);
        #pragma unroll
        for (int s = 0; s < 6; s++)
            gx[s] = __builtin_amdgcn_mfma_f32_16x16x32_f16(A2[s], B20, biasf[s], 0, 0, 0);
    }
    xload(3, xa0, xa1);

    // ---- T-loop: no LDS, no barriers; 3-unrolled for static slot regs ----
    for (int t = 0; t < T_STEPS; t += 3) {
        do_step(mkB2(xb0, xb1));                       // step t   (gx -> t+1)
        { const int tn = (t + 4 < T_STEPS) ? t + 4 : 0; xload(tn, xb0, xb1); }
        do_step(mkB2(xc0, xc1));                       // step t+1 (gx -> t+2)
        { const int tn = (t + 5 < T_STEPS) ? t + 5 : 0; xload(tn, xc0, xc1); }
        do_step(mkB2(xa0, xa1));                       // step t+2 (gx -> t+3)
        { const int tn = (t + 6 < T_STEPS) ? t + 6 : 0; xload(tn, xa0, xa1); }
    }

    // ---- epilogue: out[b][u] = b_lin[u] + sum_k tanh(h[k]) * W_lin[u][k] ----
    #pragma unroll
    for (int tau = 0; tau < 6; tau++)
        thbuf[wv][n][6 * q + tau] = tanh_f(hv[tau]);
    __syncthreads();

    #pragma unroll
    for (int tau = 0; tau < 6; tau++) {
        const int u = 6 * q + tau;
        float acc = b_lin[u];
        #pragma unroll
        for (int k = 0; k < 24; k++)
            acc = fmaf(thbuf[wv][n][k], W_lin[u * 24 + k], acc);
        out[(size_t)batch * 24 + u] = acc;
    }
}

extern "C" void kernel_launch(void* const* d_in, const int* in_sizes, int n_in,
                              void* d_out, int out_size, void* d_ws, size_t ws_size,
                              hipStream_t stream) {
    const float* x     = (const float*)d_in[0];
    const float* W_ih  = (const float*)d_in[1];
    const float* W_hh  = (const float*)d_in[2];
    const float* b_ih  = (const float*)d_in[3];
    const float* b_hh  = (const float*)d_in[4];
    const float* W_lin = (const float*)d_in[5];
    const float* b_lin = (const float*)d_in[6];
    float* out = (float*)d_out;

    const int B = in_sizes[0] / (T_STEPS * P_FEAT);   // 8192
    dim3 grid(B / 32), block(128);                    // 256 blocks x 2 waves
    lstm_bf<<<grid, block, 0, stream>>>(x, W_ih, W_hh, b_ih, b_hh, W_lin, b_lin, out);
}

// Round 5
// 242.732 us; speedup vs baseline: 1.0199x; 1.0199x over previous
//
#include <hip/hip_runtime.h>

// LSTM B=8192, T=168, P=16, H=24, gates [i,f,g,o].
// Round-14: two chains per block — barrier amortization + soft barrier.
//  - r13 post-mortem: barrier-free = only 512 waves for 1024 SIMDs; per-wave
//    issue ~1050 cyc/step (42 trans) serialized in-order -> 148 us. r12
//    spread work over 4096 waves (issue 760/SIMD) but lost ~645 cyc/step to
//    the per-step barrier convoy. Fix: keep r12's exchange, amortize barrier.
//  - NB=32 = TWO independent 16-batch chains per 8-wave block. One barrier
//    interval = both chains' step t (2 cells/lane, 14 trans, 4 MFMA/wave):
//    halves barriers per cell and fills convoy latency with chain-B issue.
//  - No LDS x-staging: x straight from global (L2 absorbs 8x wave reuse),
//    2-interval register prefetch. LDS = 4KB hx + epilogue only.
//  - Soft barrier (lgkmcnt(0)+s_barrier, NO vmcnt drain) keeps the x
//    prefetch in flight across barriers (__syncthreads would drain it).
//  - Exchange unchanged from r12: wave w owns tile mt=w; lane (q,n) gets
//    gates of unit u=8q+w; writes hx[ch][q][n][w] (b16), reads half8
//    hx[ch][q][n][0..7] (b128, conflict-free). q=3 = K-pad, stays zero.
//  - Cell math identical to r10-r13 (fused denominator, 7 trans/cell).

#define T_STEPS 168
#define P_FEAT  16
#define NBW     32   // batches per block: 2 chains x 16

typedef _Float16 half8 __attribute__((ext_vector_type(8)));
typedef float    f32x4 __attribute__((ext_vector_type(4)));

__device__ __forceinline__ float rcp_fast(float x) {
#if __has_builtin(__builtin_amdgcn_rcpf)
    return __builtin_amdgcn_rcpf(x);
#else
    return 1.0f / x;
#endif
}
__device__ __forceinline__ float exp2_fast(float x) {
#if __has_builtin(__builtin_amdgcn_exp2f)
    return __builtin_amdgcn_exp2f(x);
#else
    return exp2f(x);
#endif
}
__device__ __forceinline__ float tanh_f(float x) {
    return 1.0f - 2.0f * rcp_fast(1.0f + exp2_fast(x * 2.88539008f));
}
// lgkmcnt(0) + s_barrier, WITHOUT the vmcnt(0) drain __syncthreads adds.
// Single asm block with memory clobber: no LDS op crosses it either way.
__device__ __forceinline__ void soft_barrier() {
    asm volatile("s_waitcnt lgkmcnt(0)\n\ts_barrier" ::: "memory");
}

__global__ __launch_bounds__(512, 2) void lstm_2c(
    const float* __restrict__ x,
    const float* __restrict__ W_ih,
    const float* __restrict__ W_hh,
    const float* __restrict__ b_ih,
    const float* __restrict__ b_hh,
    const float* __restrict__ W_lin,
    const float* __restrict__ b_lin,
    float* __restrict__ out)
{
    __shared__ __align__(16) _Float16 hx[2][2][4][16][8];  // [buf][chain][q][n][slot] 4KB
    __shared__ __align__(16) float    thbuf[2][16][25];    // epilogue (pad 25)

    const int tid  = threadIdx.x;
    const int w    = tid >> 6;        // wave 0..7: tile mt = w
    const int lane = tid & 63;
    const int n    = lane & 15;       // batch col within chain
    const int q    = lane >> 4;       // k-chunk == C row-quad
    const int batchA = blockIdx.x * NBW + n;
    const int batchB = batchA + 16;

    // ---- A-fragments, direct from global (one-time, cached) ----
    // Row p of tile w: gate p%4 of unit 8*(p/4)+w; rows 12..15 zero.
    // B1 K-slot 8q+j = h-unit 8q+j (j written by wave j); q=3 pad.
    half8 WA1, WA2;
    f32x4 biasf;
    {
        const int p = n;
        const bool vrow = (p < 12);
        const int grow = vrow ? ((p & 3) * 24 + 8 * (p >> 2) + w) : 0;
        #pragma unroll
        for (int j = 0; j < 8; j++) {
            const int k = 8 * q + j;
            WA1[j] = (vrow && k < 24) ? (_Float16)W_hh[grow * 24 + k] : (_Float16)0.0f;
            WA2[j] = (vrow && k < 16) ? (_Float16)W_ih[grow * 16 + k] : (_Float16)0.0f;
        }
        const int u = 8 * q + w;      // this lane's unit (valid q<3)
        #pragma unroll
        for (int r = 0; r < 4; r++)
            biasf[r] = (q < 3) ? (b_ih[r * 24 + u] + b_hh[r * 24 + u]) : 0.0f;
    }

    // ---- zero hx (both buffers, all slots incl. q=3 pad) ----
    {
        unsigned* hz = reinterpret_cast<unsigned*>(&hx[0][0][0][0][0]);  // 1024 dw
        hz[tid] = 0u;
        hz[tid + 512] = 0u;
    }
    __syncthreads();

    const float* xrowA = x + (size_t)batchA * (T_STEPS * P_FEAT) + 8 * q;
    const float* xrowB = x + (size_t)batchB * (T_STEPS * P_FEAT) + 8 * q;

    auto xload = [&](const float* xr, int t, float4& r0, float4& r1) {
        if (q < 2) {
            const float4* p = reinterpret_cast<const float4*>(xr + (size_t)t * P_FEAT);
            r0 = p[0];
            r1 = p[1];
        }
    };
    auto mkB2 = [&](const float4& r0, const float4& r1) -> half8 {
        half8 b = {};
        if (q < 2) {
            b[0] = (_Float16)r0.x; b[1] = (_Float16)r0.y;
            b[2] = (_Float16)r0.z; b[3] = (_Float16)r0.w;
            b[4] = (_Float16)r1.x; b[5] = (_Float16)r1.y;
            b[6] = (_Float16)r1.z; b[7] = (_Float16)r1.w;
        }
        return b;
    };
    // fused-denominator cell: 7 trans
    //   c' = [c(1+Y)(1+Z) + (1+X)(Z-1)] * rcp((1+X)(1+Y)(1+Z))
    //   h  = (W-1) * rcp((1+V)(1+W)),  W = e^{2*min(c',18)}
    auto cell = [&](const f32x4& g, float& c, float& hv) {
        const float Y  = exp2_fast(g[0] * -1.44269504f);  // i
        const float X  = exp2_fast(g[1] * -1.44269504f);  // f
        const float Z  = exp2_fast(g[2] *  2.88539008f);  // g
        const float V  = exp2_fast(g[3] * -1.44269504f);  // o
        const float ax = 1.0f + X;
        const float ay = 1.0f + Y;
        const float az = 1.0f + Z;
        const float num = c * ay * az + ax * (Z - 1.0f);
        const float cn  = num * rcp_fast(ax * ay * az);
        c = cn;
        const float Wt = exp2_fast(fminf(cn, 18.0f) * 2.88539008f);
        hv = (Wt - 1.0f) * rcp_fast((1.0f + V) * (1.0f + Wt));
    };

    float cA = 0.0f, cB = 0.0f, hvA = 0.0f, hvB = 0.0f;
    f32x4 gxA, gxB;
    int bufp = 0;

    // x prefetch buffers: even/odd step parity, per chain
    float4 xae0, xae1, xbe0, xbe1;    // even: holds x(t+1) for even t
    float4 xao0, xao1, xbo0, xbo1;    // odd

    // ---- prologue: gx(0) + prefetch x(1), x(2) ----
    {
        float4 t0a0 = {0,0,0,0}, t0a1 = {0,0,0,0}, t0b0 = {0,0,0,0}, t0b1 = {0,0,0,0};
        xload(xrowA, 0, t0a0, t0a1);
        xload(xrowB, 0, t0b0, t0b1);
        xload(xrowA, 1, xae0, xae1);
        xload(xrowB, 1, xbe0, xbe1);
        xload(xrowA, 2, xao0, xao1);
        xload(xrowB, 2, xbo0, xbo1);
        gxA = __builtin_amdgcn_mfma_f32_16x16x32_f16(WA2, mkB2(t0a0, t0a1), biasf, 0, 0, 0);
        gxB = __builtin_amdgcn_mfma_f32_16x16x32_f16(WA2, mkB2(t0b0, t0b1), biasf, 0, 0, 0);
    }

    // one time-step for both chains; bufs hold x(t+1); reload for t+3
    auto one_t = [&](float4& a0, float4& a1, float4& b0, float4& b1, int tload) {
        const half8 hA = *reinterpret_cast<const half8*>(&hx[bufp][0][q][n][0]);
        const half8 hB = *reinterpret_cast<const half8*>(&hx[bufp][1][q][n][0]);
        f32x4 gA = __builtin_amdgcn_mfma_f32_16x16x32_f16(WA1, hA, gxA, 0, 0, 0);
        f32x4 gB = __builtin_amdgcn_mfma_f32_16x16x32_f16(WA1, hB, gxB, 0, 0, 0);
        gxA = __builtin_amdgcn_mfma_f32_16x16x32_f16(WA2, mkB2(a0, a1), biasf, 0, 0, 0);
        gxB = __builtin_amdgcn_mfma_f32_16x16x32_f16(WA2, mkB2(b0, b1), biasf, 0, 0, 0);
        xload(xrowA, tload, a0, a1);          // refill for t+3 (2 intervals ahead)
        xload(xrowB, tload, b0, b1);
        cell(gA, cA, hvA);
        cell(gB, cB, hvB);
        if (q < 3) {
            hx[1 - bufp][0][q][n][w] = (_Float16)hvA;
            hx[1 - bufp][1][q][n][w] = (_Float16)hvB;
        }
        bufp ^= 1;
        soft_barrier();
    };

    for (int t = 0; t < T_STEPS; t += 2) {
        one_t(xae0, xae1, xbe0, xbe1, (t + 3 < T_STEPS) ? t + 3 : 0);
        one_t(xao0, xao1, xbo0, xbo1, (t + 4 < T_STEPS) ? t + 4 : 0);
    }

    // ---- epilogue: out[b][u] = b_lin[u] + sum_k tanh(h[k]) * W_lin[u][k] ----
    if (q < 3) {
        thbuf[0][n][8 * q + w] = tanh_f(hvA);
        thbuf[1][n][8 * q + w] = tanh_f(hvB);
    }
    __syncthreads();

    if (q < 3) {
        const int u = 8 * q + w;
        const float* wl = &W_lin[u * 24];
        float accA = b_lin[u], accB = accA;
        #pragma unroll
        for (int k = 0; k < 24; k++) {
            accA = fmaf(thbuf[0][n][k], wl[k], accA);
            accB = fmaf(thbuf[1][n][k], wl[k], accB);
        }
        out[(size_t)batchA * 24 + u] = accA;
        out[(size_t)batchB * 24 + u] = accB;
    }
}

extern "C" void kernel_launch(void* const* d_in, const int* in_sizes, int n_in,
                              void* d_out, int out_size, void* d_ws, size_t ws_size,
                              hipStream_t stream) {
    const float* x     = (const float*)d_in[0];
    const float* W_ih  = (const float*)d_in[1];
    const float* W_hh  = (const float*)d_in[2];
    const float* b_ih  = (const float*)d_in[3];
    const float* b_hh  = (const float*)d_in[4];
    const float* W_lin = (const float*)d_in[5];
    const float* b_lin = (const float*)d_in[6];
    float* out = (float*)d_out;

    const int B = in_sizes[0] / (T_STEPS * P_FEAT);   // 8192
    dim3 grid(B / NBW), block(512);                   // 256 blocks x 8 waves
    lstm_2c<<<grid, block, 0, stream>>>(x, W_ih, W_hh, b_ih, b_hh, W_lin, b_lin, out);
}

// Round 6
// 197.693 us; speedup vs baseline: 1.2522x; 1.2278x over previous
//
#include <hip/hip_runtime.h>

// LSTM B=8192, T=168, P=16, H=24, gates [i,f,g,o].
// Round-15: r12 + anti-phase stagger. (r12 = best @ 98us, 1405 cyc/step.)
//  - r12/r14 post-mortem: step(r12)=1405 == 2 x per-SIMD busy(682) -> the
//    two co-resident blocks per CU run IN PHASE and serialize on the shared
//    trans/VALU pipes. In-phase is sticky: joint contention slows both
//    blocks equally, so they re-arrive at their barriers together. r14
//    (1 block/CU) proved a single block leaves ~1330 cyc idle; the second
//    block's job is to fill it, which requires anti-phase.
//  - Fix: one-time ~704-cyc s_sleep(11) for the second dispatch half
//    ((blockIdx>>8)&1): with 8 XCDs round-robin + sequential CU fill,
//    same-CU pairs are (i, i+256) -> one of each pair is offset half a
//    step. Anti-phase is self-stable afterwards.
//  - Everything else BYTE-IDENTICAL to r12: 8 waves x 1 tile, self-aligned
//    exchange (write hx[q][n][w] b16, read half8 b128), LDS x-staging,
//    fused-denominator cell (7 trans), __syncthreads per step.

#define T_STEPS 168
#define P_FEAT  16
#define TCH     84                 // t-chunk length (2 chunks)
#define NB      16                 // batches per block
#define BPAD    24                 // f16 pad per batch (2-way banks)
#define BSTR    (TCH * 16 + BPAD)  // 1368 f16 per batch

typedef _Float16 half8 __attribute__((ext_vector_type(8)));
typedef _Float16 h2    __attribute__((ext_vector_type(2)));
typedef float    f32x4 __attribute__((ext_vector_type(4)));

__device__ __forceinline__ float rcp_fast(float x) {
#if __has_builtin(__builtin_amdgcn_rcpf)
    return __builtin_amdgcn_rcpf(x);
#else
    return 1.0f / x;
#endif
}
__device__ __forceinline__ float exp2_fast(float x) {
#if __has_builtin(__builtin_amdgcn_exp2f)
    return __builtin_amdgcn_exp2f(x);
#else
    return exp2f(x);
#endif
}
__device__ __forceinline__ float tanh_f(float x) {
    return 1.0f - 2.0f * rcp_fast(1.0f + exp2_fast(x * 2.88539008f));
}
__device__ __forceinline__ h2 pack2(float a, float b) {
    h2 r; r.x = (_Float16)a; r.y = (_Float16)b; return r;
}

__global__ __launch_bounds__(512, 4) void lstm_8w(
    const float* __restrict__ x,
    const float* __restrict__ W_ih,
    const float* __restrict__ W_hh,
    const float* __restrict__ b_ih,
    const float* __restrict__ b_hh,
    const float* __restrict__ W_lin,
    const float* __restrict__ b_lin,
    float* __restrict__ out)
{
    __shared__ __align__(16) _Float16 xs16[NB * BSTR];     // 43776 B (W-stage reused)
    __shared__ __align__(16) _Float16 hx[2][4][NB][8];     //  2048 B ping-pong h
    __shared__ __align__(16) _Float16 zblk[16];            //    32 B zeros (B2 pad)
    __shared__ __align__(16) float    thbuf[NB][24];       //  1536 B epilogue

    const int tid  = threadIdx.x;
    const int w    = tid >> 6;       // wave 0..7: tile mt = w
    const int lane = tid & 63;
    const int n    = lane & 15;      // batch col (B/C) == row p supplied (A)
    const int q    = lane >> 4;      // k-chunk (A/B) == output quad (C)

    // ---- one-time: stage fused W (f32) into xs16 space ----
    float* wstage = reinterpret_cast<float*>(xs16);        // 96*40 f32
    for (int idx = tid; idx < 96 * 40; idx += 512) {
        const int j = idx / 40;
        const int k = idx - j * 40;
        wstage[idx] = (k < 24) ? W_hh[j * 24 + k] : W_ih[j * 16 + (k - 24)];
    }
    __syncthreads();

    // ---- A-fragments for this wave's tile (mt = w) ----
    // tile row p: gate p%4 of unit 8*(p/4)+mt; rows p>=12 zero.
    // A-frag layout: A[m=lane&15][k=quad*8+j].
    half8 A1, A2;
    f32x4 biasf;
    {
        const int mt = w;
        const int p  = n;
        const bool vrow = (p < 12);
        const int grow = vrow ? ((p & 3) * 24 + 8 * (p >> 2) + mt) : 0;
        #pragma unroll
        for (int j = 0; j < 8; j++) {
            const int k = q * 8 + j;
            A1[j] = (vrow && k < 24) ? (_Float16)wstage[grow * 40 + k]      : (_Float16)0.0f;
            A2[j] = (vrow && k < 16) ? (_Float16)wstage[grow * 40 + 24 + k] : (_Float16)0.0f;
        }
        #pragma unroll
        for (int r = 0; r < 4; r++) {
            const int u = 8 * q + mt;   // lane (q,n) holds gates r of unit u (q<3)
            biasf[r] = (q < 3) ? (b_ih[r * 24 + u] + b_hh[r * 24 + u]) : 0.0f;
        }
    }
    // zero hx (both buffers; q=3 rows stay 0 forever = k-pad) + zblk
    {
        unsigned* hz = reinterpret_cast<unsigned*>(&hx[0][0][0][0]);  // 512 dwords
        for (int i = tid; i < 512; i += 512) hz[i] = 0u;
        if (tid < 8) reinterpret_cast<unsigned*>(zblk)[tid] = 0u;
    }
    __syncthreads();   // wstage dead; x staging reuses the space

    // ---- anti-phase stagger: offset the second co-resident block ~704 cyc ----
    // Same-CU pairs under 8-XCD round-robin + sequential fill are (i, i+256).
    if ((blockIdx.x >> 8) & 1) __builtin_amdgcn_s_sleep(11);

    float c  = 0.0f;
    float hv = 0.0f;

    const float4* xsrc = reinterpret_cast<const float4*>(x)
                       + (size_t)(blockIdx.x * NB) * (T_STEPS * P_FEAT / 4);

    // B2 source: quads 0..1 read x halves, quads 2..3 the zero block
    const _Float16* xrowbase = (q < 2) ? &xs16[n * BSTR + q * 8] : zblk;
    const int xstep = (q < 2) ? 16 : 0;

    int bufp = 0;
    for (int ch = 0; ch < 2; ch++) {
        // stage NB x TCH x 16 f32 -> f16 (padded layout): 5376 float4
        for (int i = 0; i < 11; i++) {
            const int m = tid + 512 * i;        // 0..5375
            if (m < 5376) {
                const int b   = m / 336;        // 336 float4 per batch-chunk
                const int rem = m - b * 336;
                const float4 v = xsrc[(size_t)b * 672 + ch * 336 + rem];
                h2* dst = reinterpret_cast<h2*>(xs16) + b * (BSTR / 2) + rem * 2;
                dst[0] = pack2(v.x, v.y);
                dst[1] = pack2(v.z, v.w);
            }
        }
        __syncthreads();

        // gx prologue for t=0 of this chunk
        f32x4 gx;
        {
            const half8 B2 = *reinterpret_cast<const half8*>(xrowbase);
            gx = __builtin_amdgcn_mfma_f32_16x16x32_f16(A2, B2, biasf, 0, 0, 0);
        }

        for (int t = 0; t < TCH; t++) {
            // B1: element j = h of unit 8q+j for batch n (j=w written by wave w)
            const half8 B1 = *reinterpret_cast<const half8*>(&hx[bufp][q][n][0]);
            // prefetch next step's x fragment (last iter: dummy index 0)
            const int tn = (t + 1 < TCH) ? t + 1 : 0;
            const half8 B2n = *reinterpret_cast<const half8*>(xrowbase + tn * xstep);

            f32x4 g = __builtin_amdgcn_mfma_f32_16x16x32_f16(A1, B1, gx, 0, 0, 0);
            gx = __builtin_amdgcn_mfma_f32_16x16x32_f16(A2, B2n, biasf, 0, 0, 0);

            // fused-denominator activations: 7 trans for this lane's cell
            //   c' = [c(1+Y)(1+Z) + (1+X)(Z-1)] * rcp((1+X)(1+Y)(1+Z))
            //   h  = (W-1) * rcp((1+V)(1+W)),  W = e^{2*min(c',18)}
            {
                const float Y  = exp2_fast(g[0] * -1.44269504f);  // i
                const float X  = exp2_fast(g[1] * -1.44269504f);  // f
                const float Z  = exp2_fast(g[2] *  2.88539008f);  // g
                const float V  = exp2_fast(g[3] * -1.44269504f);  // o
                const float ax = 1.0f + X;
                const float ay = 1.0f + Y;
                const float az = 1.0f + Z;
                const float num = c * ay * az + ax * (Z - 1.0f);
                const float cn  = num * rcp_fast(ax * ay * az);
                c = cn;
                const float W  = exp2_fast(fminf(cn, 18.0f) * 2.88539008f);
                hv = (W - 1.0f) * rcp_fast((1.0f + V) * (1.0f + W));
            }

            // publish own unit to the other buffer; q=3 stays zero (k-pad)
            if (q < 3) hx[1 - bufp][q][n][w] = (_Float16)hv;
            bufp ^= 1;
            __syncthreads();
        }
    }

    // ---- epilogue: out[b][u] = b_lin[u] + sum_k tanh(h[k]) * W_lin[u][k] ----
    if (q < 3) thbuf[n][8 * q + w] = tanh_f(hv);
    __syncthreads();

    if (q < 3) {
        const int batch = blockIdx.x * NB + n;
        const int u = 8 * q + w;
        const float* wl = &W_lin[u * 24];
        float acc = b_lin[u];
        #pragma unroll
        for (int k = 0; k < 24; k++) acc = fmaf(thbuf[n][k], wl[k], acc);
        out[(size_t)batch * 24 + u] = acc;
    }
}

extern "C" void kernel_launch(void* const* d_in, const int* in_sizes, int n_in,
                              void* d_out, int out_size, void* d_ws, size_t ws_size,
                              hipStream_t stream) {
    const float* x     = (const float*)d_in[0];
    const float* W_ih  = (const float*)d_in[1];
    const float* W_hh  = (const float*)d_in[2];
    const float* b_ih  = (const float*)d_in[3];
    const float* b_hh  = (const float*)d_in[4];
    const float* W_lin = (const float*)d_in[5];
    const float* b_lin = (const float*)d_in[6];
    float* out = (float*)d_out;

    const int B = in_sizes[0] / (T_STEPS * P_FEAT);   // 8192
    dim3 grid(B / NB), block(512);                    // 512 blocks x 8 waves
    lstm_8w<<<grid, block, 0, stream>>>(x, W_ih, W_hh, b_ih, b_hh, W_lin, b_lin, out);
}